// Round 2
// baseline (2684.272 us; speedup 1.0000x reference)
//
#include <hip/hip_runtime.h>

typedef unsigned long long u64;
typedef unsigned int u32;

#define BROWS 2048
#define DDIM  1024
#define NSCH  32768
#define EPSF  1e-8f
#define BK    16
#define LDT   132   // LDS tile row stride in floats (128 + 4 pad)

// ---------- helpers ----------

__device__ __forceinline__ u64 pack_score(float v, int idx) {
    u32 u = __float_as_uint(v);
    u ^= (u & 0x80000000u) ? 0xFFFFFFFFu : 0x80000000u;  // monotone map f32 -> u32
    return ((u64)u << 32) | (u32)(0xFFFFFFFFu ^ (u32)idx);  // lower idx wins ties
}

__device__ __forceinline__ void insert4(u64& l0, u64& l1, u64& l2, u64& l3, u64 x) {
    u64 t = x, mx, mn;
    mx = l0 > t ? l0 : t; mn = l0 > t ? t : l0; l0 = mx; t = mn;
    mx = l1 > t ? l1 : t; mn = l1 > t ? t : l1; l1 = mx; t = mn;
    mx = l2 > t ? l2 : t; mn = l2 > t ? t : l2; l2 = mx; t = mn;
    l3 = l3 > t ? l3 : t;
}

__device__ __forceinline__ void stage_write(float* a, float* b, int lk, int lr,
                                            const float4& ra0, const float4& ra1,
                                            const float4& rb0, const float4& rb1) {
    a[(lk + 0) * LDT + lr] = ra0.x; a[(lk + 1) * LDT + lr] = ra0.y;
    a[(lk + 2) * LDT + lr] = ra0.z; a[(lk + 3) * LDT + lr] = ra0.w;
    a[(lk + 4) * LDT + lr] = ra1.x; a[(lk + 5) * LDT + lr] = ra1.y;
    a[(lk + 6) * LDT + lr] = ra1.z; a[(lk + 7) * LDT + lr] = ra1.w;
    b[(lk + 0) * LDT + lr] = rb0.x; b[(lk + 1) * LDT + lr] = rb0.y;
    b[(lk + 2) * LDT + lr] = rb0.z; b[(lk + 3) * LDT + lr] = rb0.w;
    b[(lk + 4) * LDT + lr] = rb1.x; b[(lk + 5) * LDT + lr] = rb1.y;
    b[(lk + 6) * LDT + lr] = rb1.z; b[(lk + 7) * LDT + lr] = rb1.w;
}

__device__ __forceinline__ void compute_tile(const float* a, const float* b,
                                             int tx, int ty, float acc[8][8]) {
#pragma unroll
    for (int kk = 0; kk < BK; ++kk) {
        const float* ap = a + kk * LDT + ty * 8;
        const float* bp = b + kk * LDT + tx * 8;
        float4 a0 = *reinterpret_cast<const float4*>(ap);
        float4 a1 = *reinterpret_cast<const float4*>(ap + 4);
        float4 b0 = *reinterpret_cast<const float4*>(bp);
        float4 b1 = *reinterpret_cast<const float4*>(bp + 4);
        float av[8] = {a0.x, a0.y, a0.z, a0.w, a1.x, a1.y, a1.z, a1.w};
        float bv[8] = {b0.x, b0.y, b0.z, b0.w, b1.x, b1.y, b1.z, b1.w};
#pragma unroll
        for (int i = 0; i < 8; ++i)
#pragma unroll
            for (int j = 0; j < 8; ++j)
                acc[i][j] = fmaf(av[i], bv[j], acc[i][j]);
    }
}

// ---------- kernel 1: pq = query @ W^T + b ----------
// grid = 16 row-tiles * 8 col-tiles = 128 blocks, 256 threads

__global__ __launch_bounds__(256) void proj_kernel(const float* __restrict__ A,
                                                   const float* __restrict__ Wm,
                                                   const float* __restrict__ bias,
                                                   float* __restrict__ pq) {
    __shared__ __align__(16) float at[2][BK * LDT];
    __shared__ __align__(16) float bt[2][BK * LDT];
    int tid = threadIdx.x;
    int rt = blockIdx.x & 15;
    int ct = blockIdx.x >> 4;
    int m0 = rt * 128, n0 = ct * 128;
    int lr = tid >> 1;
    int lk = (tid & 1) * 8;
    int tx = tid & 15, ty = tid >> 4;
    const float* aptr = A + (size_t)(m0 + lr) * DDIM + lk;
    const float* bptr = Wm + (size_t)(n0 + lr) * DDIM + lk;

    float acc[8][8] = {};
    float4 ra0, ra1, rb0, rb1;
    ra0 = *reinterpret_cast<const float4*>(aptr);
    ra1 = *reinterpret_cast<const float4*>(aptr + 4);
    rb0 = *reinterpret_cast<const float4*>(bptr);
    rb1 = *reinterpret_cast<const float4*>(bptr + 4);
    stage_write(at[0], bt[0], lk, lr, ra0, ra1, rb0, rb1);
    __syncthreads();

    for (int kt = 0; kt < DDIM / BK; ++kt) {
        int cur = kt & 1;
        if (kt < DDIM / BK - 1) {
            const float* ap = aptr + (kt + 1) * BK;
            const float* bp = bptr + (kt + 1) * BK;
            ra0 = *reinterpret_cast<const float4*>(ap);
            ra1 = *reinterpret_cast<const float4*>(ap + 4);
            rb0 = *reinterpret_cast<const float4*>(bp);
            rb1 = *reinterpret_cast<const float4*>(bp + 4);
        }
        compute_tile(at[cur], bt[cur], tx, ty, acc);
        if (kt < DDIM / BK - 1)
            stage_write(at[cur ^ 1], bt[cur ^ 1], lk, lr, ra0, ra1, rb0, rb1);
        __syncthreads();
    }

    int m = m0 + ty * 8;
    int n = n0 + tx * 8;
    float bb[8];
#pragma unroll
    for (int c = 0; c < 8; ++c) bb[c] = bias[n + c];
#pragma unroll
    for (int r = 0; r < 8; ++r) {
        float4 o0 = {acc[r][0] + bb[0], acc[r][1] + bb[1], acc[r][2] + bb[2], acc[r][3] + bb[3]};
        float4 o1 = {acc[r][4] + bb[4], acc[r][5] + bb[5], acc[r][6] + bb[6], acc[r][7] + bb[7]};
        *reinterpret_cast<float4*>(pq + (size_t)(m + r) * DDIM + n) = o0;
        *reinterpret_cast<float4*>(pq + (size_t)(m + r) * DDIM + n + 4) = o1;
    }
}

// ---------- kernel 2: row L2 norms (cols = 1024, 256 threads, 1 block/row) ----------

__global__ __launch_bounds__(256) void rownorm_kernel(const float* __restrict__ in,
                                                      float* __restrict__ out) {
    int row = blockIdx.x;
    const float4* p = reinterpret_cast<const float4*>(in + (size_t)row * DDIM);
    int t = threadIdx.x;
    float4 v = p[t];
    float s = v.x * v.x + v.y * v.y + v.z * v.z + v.w * v.w;
#pragma unroll
    for (int m = 32; m > 0; m >>= 1) s += __shfl_down(s, m, 64);
    __shared__ float wsum[4];
    int lane = t & 63, w = t >> 6;
    if (lane == 0) wsum[w] = s;
    __syncthreads();
    if (t == 0) out[row] = sqrtf(wsum[0] + wsum[1] + wsum[2] + wsum[3]);
}

// ---------- kernel 3: scores GEMM + fused per-row top-4 per 2048-col chunk ----------
// grid: 256 blocks = (row-tile 16) x (col-chunk 16); chunk = 16 sub-tiles of 128 cols

__global__ __launch_bounds__(256) void score_kernel(const float* __restrict__ pq,
                                                    const float* __restrict__ keys,
                                                    const float* __restrict__ qn,
                                                    const float* __restrict__ kn,
                                                    const int* __restrict__ act,
                                                    u64* __restrict__ cand) {
    __shared__ __align__(16) float at[2][BK * LDT];
    __shared__ __align__(16) float bt[2][BK * LDT];
    int tid = threadIdx.x;
    int cc = blockIdx.x & 15;   // col chunk (2048 cols) -> XCD-pinned since 16 % 8 == 0
    int rt = blockIdx.x >> 4;   // row tile
    int m0 = rt * 128;
    int lr = tid >> 1;
    int lk = (tid & 1) * 8;
    int tx = tid & 15, ty = tid >> 4;
    const float* aptr = pq + (size_t)(m0 + lr) * DDIM + lk;

    float qnv[8];
#pragma unroll
    for (int r = 0; r < 8; ++r) qnv[r] = qn[m0 + ty * 8 + r];

    u64 loc[8][4];
#pragma unroll
    for (int r = 0; r < 8; ++r)
#pragma unroll
        for (int j = 0; j < 4; ++j) loc[r][j] = 0ULL;

    for (int st = 0; st < 16; ++st) {
        int n0 = cc * 2048 + st * 128;
        const float* bptr = keys + (size_t)(n0 + lr) * DDIM + lk;
        float acc[8][8] = {};
        float4 ra0, ra1, rb0, rb1;
        ra0 = *reinterpret_cast<const float4*>(aptr);
        ra1 = *reinterpret_cast<const float4*>(aptr + 4);
        rb0 = *reinterpret_cast<const float4*>(bptr);
        rb1 = *reinterpret_cast<const float4*>(bptr + 4);
        stage_write(at[0], bt[0], lk, lr, ra0, ra1, rb0, rb1);
        __syncthreads();

        for (int kt = 0; kt < DDIM / BK; ++kt) {
            int cur = kt & 1;
            if (kt < DDIM / BK - 1) {
                const float* ap = aptr + (kt + 1) * BK;
                const float* bp = bptr + (kt + 1) * BK;
                ra0 = *reinterpret_cast<const float4*>(ap);
                ra1 = *reinterpret_cast<const float4*>(ap + 4);
                rb0 = *reinterpret_cast<const float4*>(bp);
                rb1 = *reinterpret_cast<const float4*>(bp + 4);
            }
            compute_tile(at[cur], bt[cur], tx, ty, acc);
            if (kt < DDIM / BK - 1)
                stage_write(at[cur ^ 1], bt[cur ^ 1], lk, lr, ra0, ra1, rb0, rb1);
            __syncthreads();
        }

        // epilogue: scores + insert into per-thread top-4
        float knv[8], mk[8];
#pragma unroll
        for (int c = 0; c < 8; ++c) {
            int n = n0 + tx * 8 + c;
            knv[c] = kn[n];
            mk[c] = (act[n] != 0) ? 1.0f : 0.0f;
        }
#pragma unroll
        for (int r = 0; r < 8; ++r) {
#pragma unroll
            for (int c = 0; c < 8; ++c) {
                int n = n0 + tx * 8 + c;
                float denom = fmaxf(qnv[r] * knv[c], EPSF);
                float score = (acc[r][c] / denom) * mk[c];  // exact ref semantics incl. +/-0
                insert4(loc[r][0], loc[r][1], loc[r][2], loc[r][3], pack_score(score, n));
            }
        }
    }

    // merge top-4 across the 16 tx-lanes of each row group, write candidates
#pragma unroll
    for (int r = 0; r < 8; ++r) {
        u64 l0 = loc[r][0], l1 = loc[r][1], l2 = loc[r][2], l3 = loc[r][3];
#pragma unroll
        for (int md = 1; md < 16; md <<= 1) {
            u64 o0 = __shfl_xor(l0, md, 64);
            u64 o1 = __shfl_xor(l1, md, 64);
            u64 o2 = __shfl_xor(l2, md, 64);
            u64 o3 = __shfl_xor(l3, md, 64);
            insert4(l0, l1, l2, l3, o0);
            insert4(l0, l1, l2, l3, o1);
            insert4(l0, l1, l2, l3, o2);
            insert4(l0, l1, l2, l3, o3);
        }
        if (tx == 0) {
            int grow = m0 + ty * 8 + r;
            u64* c = cand + ((size_t)grow * 16 + cc) * 4;
            c[0] = l0; c[1] = l1; c[2] = l2; c[3] = l3;
        }
    }
}

// ---------- kernel 4: final merge (64 candidates/row) + gather values + mean ----------

__global__ __launch_bounds__(256) void select_kernel(const u64* __restrict__ cand,
                                                     const int* __restrict__ act,
                                                     const float* __restrict__ values,
                                                     float* __restrict__ out) {
    int row = blockIdx.x;
    __shared__ int sidx[4];
    __shared__ float sact[4];
    __shared__ float scnt;
    if (threadIdx.x == 0) {
        u64 l0 = 0, l1 = 0, l2 = 0, l3 = 0;
        const u64* c = cand + (size_t)row * 64;
        for (int i = 0; i < 64; ++i) insert4(l0, l1, l2, l3, c[i]);
        u64 ls[4] = {l0, l1, l2, l3};
        int cnt = 0;
        for (int j = 0; j < 4; ++j) {
            int idx = (int)(0xFFFFFFFFu ^ (u32)ls[j]);
            int a = (act[idx] != 0) ? 1 : 0;
            sidx[j] = idx;
            sact[j] = a ? 1.0f : 0.0f;
            cnt += a;
        }
        scnt = (float)cnt;
    }
    __syncthreads();
    int d0 = threadIdx.x * 4;
    float4 s = {0.f, 0.f, 0.f, 0.f};
#pragma unroll
    for (int j = 0; j < 4; ++j) {
        if (sact[j] != 0.f) {
            float4 v = *reinterpret_cast<const float4*>(values + (size_t)sidx[j] * DDIM + d0);
            s.x += v.x; s.y += v.y; s.z += v.z; s.w += v.w;
        }
    }
    float dn = fmaxf(scnt, 1.0f);
    float4 o = {s.x / dn, s.y / dn, s.z / dn, s.w / dn};
    *reinterpret_cast<float4*>(out + (size_t)row * DDIM + d0) = o;
}

// ---------- launcher ----------

extern "C" void kernel_launch(void* const* d_in, const int* in_sizes, int n_in,
                              void* d_out, int out_size, void* d_ws, size_t ws_size,
                              hipStream_t stream) {
    const float* query  = (const float*)d_in[0];
    const float* Wm     = (const float*)d_in[1];
    const float* bias   = (const float*)d_in[2];
    const float* keys   = (const float*)d_in[3];
    const float* values = (const float*)d_in[4];
    const int*   act    = (const int*)d_in[5];
    float* out = (float*)d_out;

    char* ws = (char*)d_ws;
    float* pq   = (float*)(ws);                          // 2048*1024*4 = 8388608
    float* qn   = (float*)(ws + 8388608);                // 2048*4      = 8192
    float* kn   = (float*)(ws + 8396800);                // 32768*4     = 131072
    u64*   cand = (u64*)(ws + 8527872);                  // 2048*16*4*8 = 1048576

    proj_kernel<<<dim3(128), dim3(256), 0, stream>>>(query, Wm, bias, pq);
    rownorm_kernel<<<dim3(BROWS), dim3(256), 0, stream>>>(pq, qn);
    rownorm_kernel<<<dim3(NSCH), dim3(256), 0, stream>>>(keys, kn);
    score_kernel<<<dim3(256), dim3(256), 0, stream>>>(pq, keys, qn, kn, act, cand);
    select_kernel<<<dim3(BROWS), dim3(256), 0, stream>>>(cand, act, values, out);
}